// Round 13
// baseline (272.630 us; speedup 1.0000x reference)
//
#include <hip/hip_runtime.h>
#include <stdint.h>

#define NUM_HEADS 12
#define DH 64
#define SEQ 2048
#define BATCH 2
#define DM 768
#define NQK 1536  // Q cols [0,768) | K cols [768,1536)
#define LOG2E 1.44269504088896340736f

typedef short short8 __attribute__((ext_vector_type(8)));
typedef short short4_t __attribute__((ext_vector_type(4)));
typedef float f32x4 __attribute__((ext_vector_type(4)));

__device__ __forceinline__ short bf16_rne(float f) {
    union { float f; uint32_t u; } v; v.f = f;
    return (short)((v.u + 0x7FFFu + ((v.u >> 16) & 1u)) >> 16);
}

// ---------------- Kernel 0: prep (wt | mpack), branch on blockIdx ----------------
__global__ __launch_bounds__(256) void prep_kernel(const float* __restrict__ Wq,
                                                   const float* __restrict__ Wk,
                                                   const int* __restrict__ mask,
                                                   short* __restrict__ Wt,
                                                   unsigned long long* __restrict__ Mb) {
    __shared__ float tile[32][33];
    const int bid = blockIdx.x;
    const int t = threadIdx.x;
    if (bid < 1152) {
        int n0 = (bid % 48) * 32;
        int k0 = (bid / 48) * 32;
        int tx = t & 31;
        int ty = t >> 5;
        const float* src = (n0 < DM) ? Wq : Wk;
        int nn0 = (n0 < DM) ? n0 : n0 - DM;
#pragma unroll
        for (int j = 0; j < 4; ++j) {
            int k = ty + 8 * j;
            tile[k][tx] = src[(size_t)(k0 + k) * DM + nn0 + tx];
        }
        __syncthreads();
#pragma unroll
        for (int j = 0; j < 4; ++j) {
            int n = ty + 8 * j;
            Wt[(size_t)(n0 + n) * DM + k0 + tx] = bf16_rne(tile[tx][n]);
        }
    } else {
        // ---- mpack ----
        int wid = (bid - 1152) * 4 + (t >> 6);
        int lane = t & 63;
        size_t base = (size_t)wid * 8;
#pragma unroll
        for (int i = 0; i < 8; ++i) {
            size_t w = base + i;
            int v = mask[w * 64 + lane];
            unsigned long long bal = __ballot(v != 0);
            if (lane == 0) Mb[w] = bal;
        }
    }
}

// ---------------- Kernel 1: projection GEMM (128x128, BK=64; A staged from f32 x) ----------------
__global__ __launch_bounds__(256) void proj_kernel(const float* __restrict__ x,
                                                   const short* __restrict__ Wt,
                                                   const float* __restrict__ bq,
                                                   const float* __restrict__ bk,
                                                   short* __restrict__ QK) {
    __shared__ short As[128 * 72];
    __shared__ short Bs[128 * 72];
    const int m0 = blockIdx.x * 128;
    const int n0 = blockIdx.y * 128;
    const int t = threadIdx.x;
    const int lane = t & 63;
    const int w = t >> 6;
    const int wr = w >> 1, wc = w & 1;
    const int lr = lane & 15;
    const int lk = lane >> 4;

    f32x4 acc[4][4] = {};

    for (int k0 = 0; k0 < DM; k0 += 64) {
#pragma unroll
        for (int j = 0; j < 4; ++j) {
            int idx = t + 256 * j;          // 0..1023
            int row = idx >> 3;             // 0..127
            int ch = idx & 7;               // 8 chunks of 8 elems = 64 k
            const float* xp = &x[(size_t)(m0 + row) * DM + k0 + ch * 8];
            f32x4 v0 = *(const f32x4*)xp;
            f32x4 v1 = *(const f32x4*)(xp + 4);
            short8 s;
#pragma unroll
            for (int e = 0; e < 4; ++e) { s[e] = bf16_rne(v0[e]); s[e + 4] = bf16_rne(v1[e]); }
            *(short8*)&As[row * 72 + ch * 8] = s;
            *(short8*)&Bs[row * 72 + ch * 8] =
                *(const short8*)&Wt[(size_t)(n0 + row) * DM + k0 + ch * 8];
        }
        __syncthreads();
#pragma unroll
        for (int kk = 0; kk < 2; ++kk) {
            short8 a[4], bfr[4];
#pragma unroll
            for (int m = 0; m < 4; ++m)
                a[m] = *(short8*)&As[(wr * 64 + m * 16 + lr) * 72 + kk * 32 + lk * 8];
#pragma unroll
            for (int n = 0; n < 4; ++n)
                bfr[n] = *(short8*)&Bs[(wc * 64 + n * 16 + lr) * 72 + kk * 32 + lk * 8];
#pragma unroll
            for (int m = 0; m < 4; ++m)
#pragma unroll
                for (int n = 0; n < 4; ++n)
                    acc[m][n] = __builtin_amdgcn_mfma_f32_16x16x32_bf16(a[m], bfr[n], acc[m][n], 0, 0, 0);
        }
        __syncthreads();
    }

    const int orow = m0 + wr * 64;
    const int ocol = n0 + wc * 64;
#pragma unroll
    for (int m = 0; m < 4; ++m) {
#pragma unroll
        for (int n = 0; n < 4; ++n) {
            int col = ocol + n * 16 + lr;
            float bias = (col < DM) ? bq[col] : bk[col - DM];
            float scale = (col < DM) ? 0.125f * LOG2E : 1.0f;
#pragma unroll
            for (int r = 0; r < 4; ++r) {
                int row = orow + m * 16 + lk * 4 + r;
                QK[(size_t)row * NQK + col] = bf16_rne((acc[m][n][r] + bias) * scale);
            }
        }
    }
}

// ---------------- Kernel 2: attn (R11: LDS store-transpose + XCD clustering) ----------------
__global__ __launch_bounds__(256) void attn_kernel(const short* __restrict__ QK,
                                                   const unsigned long long* __restrict__ Mb,
                                                   float* __restrict__ out) {
    __shared__ short Ks[2][64 * 72];   // 18.4 KB
    __shared__ float Pb[64 * 132];     // 33.8 KB
    const int bid = blockIdx.x;
    const int xcd = bid & 7;
    const int jj = bid >> 3;
    const int bh = xcd * 3 + (jj >> 5);
    const int qblk = jj & 31;
    const int b = bh / NUM_HEADS;
    const int h = bh % NUM_HEADS;
    const int t = threadIdx.x;
    const int lane = t & 63;
    const int w = t >> 6;
    const int lr = lane & 15;
    const int lk = lane >> 4;
    const int wq = qblk * 64 + w * 16;

    short8 aq[2];
#pragma unroll
    for (int ks = 0; ks < 2; ++ks)
        aq[ks] = *(const short8*)&QK[(size_t)(b * SEQ + wq + lr) * NQK + h * DH + ks * 32 + lk * 8];

    float lrow[4] = {0.f, 0.f, 0.f, 0.f};
    const size_t mrow0 = (size_t)b * SEQ * (SEQ / 64);
    const int srow = t >> 3, sch = t & 7;

#define ATT_STAGE(KT)                                                                             \
    {                                                                                             \
        _Pragma("unroll") for (int tb = 0; tb < 2; ++tb) {                                        \
            *(short8*)&Ks[tb][srow * 72 + sch * 8] =                                              \
                *(const short8*)&QK[(size_t)(b * SEQ + (KT) + tb * 64 + srow) * NQK + DM +        \
                                    h * DH + sch * 8];                                            \
            *(short8*)&Ks[tb][(srow + 32) * 72 + sch * 8] =                                       \
                *(const short8*)&QK[(size_t)(b * SEQ + (KT) + tb * 64 + srow + 32) * NQK + DM +   \
                                    h * DH + sch * 8];                                            \
        }                                                                                         \
    }

    // ---- pass A: masked sum of exp2 ----
    for (int kt = 0; kt < SEQ; kt += 128) {
        ATT_STAGE(kt)
        __syncthreads();
#pragma unroll
        for (int tb = 0; tb < 2; ++tb) {
            f32x4 sc[4];
#pragma unroll
            for (int nf = 0; nf < 4; ++nf) {
                short8 k0 = *(short8*)&Ks[tb][(nf * 16 + lr) * 72 + lk * 8];
                short8 k1 = *(short8*)&Ks[tb][(nf * 16 + lr) * 72 + 32 + lk * 8];
                f32x4 a = {0.f, 0.f, 0.f, 0.f};
                a = __builtin_amdgcn_mfma_f32_16x16x32_bf16(aq[0], k0, a, 0, 0, 0);
                a = __builtin_amdgcn_mfma_f32_16x16x32_bf16(aq[1], k1, a, 0, 0, 0);
                sc[nf] = a;
            }
#pragma unroll
            for (int r = 0; r < 4; ++r) {
                int q = wq + lk * 4 + r;
                unsigned long long mbs = Mb[mrow0 + (size_t)q * 32 + ((kt >> 6) + tb)] >> lr;
                float s = 0.f;
#pragma unroll
                for (int nf = 0; nf < 4; ++nf) {
                    float e = __builtin_amdgcn_exp2f(sc[nf][r]);
                    s += ((mbs >> (nf * 16)) & 1ull) ? e : 0.f;
                }
                lrow[r] += s;
            }
        }
        __syncthreads();
    }

    // ---- reduce over the 16 key-lanes ----
    float inv[4];
#pragma unroll
    for (int r = 0; r < 4; ++r) {
        float l = lrow[r];
        l += __shfl_xor(l, 1, 64);
        l += __shfl_xor(l, 2, 64);
        l += __shfl_xor(l, 4, 64);
        l += __shfl_xor(l, 8, 64);
        inv[r] = 1.0f / l;
    }

    // ---- pass B: recompute -> Pb (LDS) -> 512B-segment coalesced stores ----
    const size_t obase0 = ((size_t)((b * NUM_HEADS + h) * SEQ) + qblk * 64) * SEQ;
    for (int kt = 0; kt < SEQ; kt += 128) {
        ATT_STAGE(kt)
        __syncthreads();   // Ks ready; also fences previous group's Pb reads
#pragma unroll
        for (int tb = 0; tb < 2; ++tb) {
            f32x4 sc[4];
#pragma unroll
            for (int nf = 0; nf < 4; ++nf) {
                short8 k0 = *(short8*)&Ks[tb][(nf * 16 + lr) * 72 + lk * 8];
                short8 k1 = *(short8*)&Ks[tb][(nf * 16 + lr) * 72 + 32 + lk * 8];
                f32x4 a = {0.f, 0.f, 0.f, 0.f};
                a = __builtin_amdgcn_mfma_f32_16x16x32_bf16(aq[0], k0, a, 0, 0, 0);
                a = __builtin_amdgcn_mfma_f32_16x16x32_bf16(aq[1], k1, a, 0, 0, 0);
                sc[nf] = a;
            }
#pragma unroll
            for (int r = 0; r < 4; ++r) {
                int q = wq + lk * 4 + r;
                int qloc = w * 16 + lk * 4 + r;
                unsigned long long mbs = Mb[mrow0 + (size_t)q * 32 + ((kt >> 6) + tb)] >> lr;
#pragma unroll
                for (int nf = 0; nf < 4; ++nf) {
                    float p = __builtin_amdgcn_exp2f(sc[nf][r]) * inv[r];
                    Pb[qloc * 132 + tb * 64 + nf * 16 + lr] =
                        ((mbs >> (nf * 16)) & 1ull) ? p : 0.f;
                }
            }
        }
        __syncthreads();   // Pb ready
#pragma unroll
        for (int g = 0; g < 8; ++g) {
            int row = g * 8 + (t >> 5);
            int col = (t & 31) * 4;
            *(f32x4*)&out[obase0 + (size_t)row * SEQ + kt + col] = *(f32x4*)&Pb[row * 132 + col];
        }
    }
#undef ATT_STAGE
}

extern "C" void kernel_launch(void* const* d_in, const int* in_sizes, int n_in,
                              void* d_out, int out_size, void* d_ws, size_t ws_size,
                              hipStream_t stream) {
    (void)in_sizes; (void)n_in; (void)out_size; (void)ws_size;
    const float* x = (const float*)d_in[0];
    const int* mask = (const int*)d_in[1];
    const float* Wq = (const float*)d_in[2];
    const float* bq = (const float*)d_in[3];
    const float* Wk = (const float*)d_in[4];
    const float* bk = (const float*)d_in[5];
    float* out = (float*)d_out;

    short* Wt = (short*)d_ws;                           // 1536*768 bf16
    short* QK = Wt + (size_t)NQK * DM;                  // 4096*1536 bf16
    unsigned long long* Mb =
        (unsigned long long*)(QK + (size_t)BATCH * SEQ * NQK);  // 131072 u64

    prep_kernel<<<dim3(1152 + 4096), 256, 0, stream>>>(Wq, Wk, mask, Wt, Mb);
    proj_kernel<<<dim3(BATCH * SEQ / 128, NQK / 128), 256, 0, stream>>>(x, Wt, bq, bk, QK);
    // MEASUREMENT PROBE: attn launched twice (identical output; graph-serial).
    // dur_us - 155 ≈ T_attn + one launch gap. Revert to single launch next round.
    attn_kernel<<<dim3(768), 256, 0, stream>>>(QK, Mb, out);
    attn_kernel<<<dim3(768), 256, 0, stream>>>(QK, Mb, out);
}

// Round 14
// 202.665 us; speedup vs baseline: 1.3452x; 1.3452x over previous
//
#include <hip/hip_runtime.h>
#include <stdint.h>

#define NUM_HEADS 12
#define DH 64
#define SEQ 2048
#define BATCH 2
#define DM 768
#define NQK 1536  // Q cols [0,768) | K cols [768,1536)
#define LOG2E 1.44269504088896340736f

typedef short short8 __attribute__((ext_vector_type(8)));
typedef short short4_t __attribute__((ext_vector_type(4)));
typedef float f32x4 __attribute__((ext_vector_type(4)));

__device__ __forceinline__ short bf16_rne(float f) {
    union { float f; uint32_t u; } v; v.f = f;
    return (short)((v.u + 0x7FFFu + ((v.u >> 16) & 1u)) >> 16);
}

// ---------------- Kernel 0: prep (wt | mpack), branch on blockIdx ----------------
__global__ __launch_bounds__(256) void prep_kernel(const float* __restrict__ Wq,
                                                   const float* __restrict__ Wk,
                                                   const int* __restrict__ mask,
                                                   short* __restrict__ Wt,
                                                   unsigned long long* __restrict__ Mb) {
    __shared__ float tile[32][33];
    const int bid = blockIdx.x;
    const int t = threadIdx.x;
    if (bid < 1152) {
        int n0 = (bid % 48) * 32;
        int k0 = (bid / 48) * 32;
        int tx = t & 31;
        int ty = t >> 5;
        const float* src = (n0 < DM) ? Wq : Wk;
        int nn0 = (n0 < DM) ? n0 : n0 - DM;
#pragma unroll
        for (int j = 0; j < 4; ++j) {
            int k = ty + 8 * j;
            tile[k][tx] = src[(size_t)(k0 + k) * DM + nn0 + tx];
        }
        __syncthreads();
#pragma unroll
        for (int j = 0; j < 4; ++j) {
            int n = ty + 8 * j;
            Wt[(size_t)(n0 + n) * DM + k0 + tx] = bf16_rne(tile[tx][n]);
        }
    } else {
        int wid = (bid - 1152) * 4 + (t >> 6);
        int lane = t & 63;
        size_t base = (size_t)wid * 8;
#pragma unroll
        for (int i = 0; i < 8; ++i) {
            size_t w = base + i;
            int v = mask[w * 64 + lane];
            unsigned long long bal = __ballot(v != 0);
            if (lane == 0) Mb[w] = bal;
        }
    }
}

// ---------------- Kernel 1: projection GEMM (128x128, BK=64; A staged from f32 x) ----------------
__global__ __launch_bounds__(256) void proj_kernel(const float* __restrict__ x,
                                                   const short* __restrict__ Wt,
                                                   const float* __restrict__ bq,
                                                   const float* __restrict__ bk,
                                                   short* __restrict__ QK) {
    __shared__ short As[128 * 72];
    __shared__ short Bs[128 * 72];
    const int m0 = blockIdx.x * 128;
    const int n0 = blockIdx.y * 128;
    const int t = threadIdx.x;
    const int lane = t & 63;
    const int w = t >> 6;
    const int wr = w >> 1, wc = w & 1;
    const int lr = lane & 15;
    const int lk = lane >> 4;

    f32x4 acc[4][4] = {};

    for (int k0 = 0; k0 < DM; k0 += 64) {
#pragma unroll
        for (int j = 0; j < 4; ++j) {
            int idx = t + 256 * j;
            int row = idx >> 3;
            int ch = idx & 7;
            const float* xp = &x[(size_t)(m0 + row) * DM + k0 + ch * 8];
            f32x4 v0 = *(const f32x4*)xp;
            f32x4 v1 = *(const f32x4*)(xp + 4);
            short8 s;
#pragma unroll
            for (int e = 0; e < 4; ++e) { s[e] = bf16_rne(v0[e]); s[e + 4] = bf16_rne(v1[e]); }
            *(short8*)&As[row * 72 + ch * 8] = s;
            *(short8*)&Bs[row * 72 + ch * 8] =
                *(const short8*)&Wt[(size_t)(n0 + row) * DM + k0 + ch * 8];
        }
        __syncthreads();
#pragma unroll
        for (int kk = 0; kk < 2; ++kk) {
            short8 a[4], bfr[4];
#pragma unroll
            for (int m = 0; m < 4; ++m)
                a[m] = *(short8*)&As[(wr * 64 + m * 16 + lr) * 72 + kk * 32 + lk * 8];
#pragma unroll
            for (int n = 0; n < 4; ++n)
                bfr[n] = *(short8*)&Bs[(wc * 64 + n * 16 + lr) * 72 + kk * 32 + lk * 8];
#pragma unroll
            for (int m = 0; m < 4; ++m)
#pragma unroll
                for (int n = 0; n < 4; ++n)
                    acc[m][n] = __builtin_amdgcn_mfma_f32_16x16x32_bf16(a[m], bfr[n], acc[m][n], 0, 0, 0);
        }
        __syncthreads();
    }

    const int orow = m0 + wr * 64;
    const int ocol = n0 + wc * 64;
#pragma unroll
    for (int m = 0; m < 4; ++m) {
#pragma unroll
        for (int n = 0; n < 4; ++n) {
            int col = ocol + n * 16 + lr;
            float bias = (col < DM) ? bq[col] : bk[col - DM];
            float scale = (col < DM) ? 0.125f * LOG2E : 1.0f;
#pragma unroll
            for (int r = 0; r < 4; ++r) {
                int row = orow + m * 16 + lk * 4 + r;
                QK[(size_t)row * NQK + col] = bf16_rne((acc[m][n][r] + bias) * scale);
            }
        }
    }
}

// ---------------- Kernel 2: attn, 8-wave A/B pipelined ----------------
// 512 thr: waves 0-3 = A-half (denominators), 4-7 = B-half (probs+store).
// Rows: set0 = qblk*64+[0,32), set1 = +[32,64). 48 shared K-group steps:
// phase0: A(set0); phase1: A(set1) || B(set0)+stores; phase2: B(set1).
// Per compute wave: rh = rows sub-half (16), tbw = 64-key tile of the 128-key group.
__global__ __launch_bounds__(512) void attn_kernel(const short* __restrict__ QK,
                                                   const unsigned long long* __restrict__ Mb,
                                                   float* __restrict__ out) {
    __shared__ short Ks[2][64 * 72];          // 18.4 KB (128 keys)
    __shared__ float Pb[32 * 132];            // 16.9 KB
    __shared__ float red[2][2][2][16];        // [set][tb][rh][row] partial denominators
    const int bid = blockIdx.x;
    const int xcd = bid & 7;
    const int jj = bid >> 3;
    const int bh = xcd * 3 + (jj >> 5);
    const int qblk = jj & 31;
    const int b = bh / NUM_HEADS;
    const int h = bh % NUM_HEADS;
    const int t = threadIdx.x;
    const int lane = t & 63;
    const int w = t >> 6;       // 0..7
    const int half = w >> 2;    // 0=A, 1=B
    const int sub = w & 3;
    const int rh = sub & 1;     // 16-row sub-half within the 32-row set
    const int tbw = sub >> 1;   // which 64-key tile of the 128-key group
    const int lr = lane & 15;
    const int lk = lane >> 4;
    const size_t mrow0 = (size_t)b * SEQ * 32;
    const int srow = t >> 3, sch = t & 7;   // staging: 64 rows x 8 chunks

#define STAGE(G)                                                                              \
    {                                                                                         \
        const short* kp =                                                                     \
            &QK[(size_t)(b * SEQ + (G) * 128 + srow) * NQK + DM + h * DH + sch * 8];          \
        *(short8*)&Ks[0][srow * 72 + sch * 8] = *(const short8*)kp;                           \
        *(short8*)&Ks[1][srow * 72 + sch * 8] = *(const short8*)(kp + (size_t)64 * NQK);      \
    }

    short8 aq0, aq1;
    float lsum[4] = {0.f, 0.f, 0.f, 0.f};
    float inv[4] = {0.f, 0.f, 0.f, 0.f};

    STAGE(0)
    __syncthreads();

    for (int gg = 0; gg < 48; ++gg) {
        const int g = gg & 15;
        const int phase = gg >> 4;

        // ---------- compute ----------
        if (half == 0 && phase < 2) {
            const int set = phase;
            const int rowbase = qblk * 64 + set * 32 + rh * 16;
            if (g == 0) {
                aq0 = *(const short8*)&QK[(size_t)(b * SEQ + rowbase + lr) * NQK + h * DH + lk * 8];
                aq1 = *(const short8*)&QK[(size_t)(b * SEQ + rowbase + lr) * NQK + h * DH + 32 + lk * 8];
                lsum[0] = lsum[1] = lsum[2] = lsum[3] = 0.f;
            }
            unsigned long long mq[4];
#pragma unroll
            for (int r = 0; r < 4; ++r) {
                int q = rowbase + lk * 4 + r;
                mq[r] = Mb[mrow0 + (size_t)q * 32 + g * 2 + tbw] >> lr;
            }
#pragma unroll
            for (int nf = 0; nf < 4; ++nf) {
                short8 k0 = *(short8*)&Ks[tbw][(nf * 16 + lr) * 72 + lk * 8];
                short8 k1 = *(short8*)&Ks[tbw][(nf * 16 + lr) * 72 + 32 + lk * 8];
                f32x4 a = {0.f, 0.f, 0.f, 0.f};
                a = __builtin_amdgcn_mfma_f32_16x16x32_bf16(aq0, k0, a, 0, 0, 0);
                a = __builtin_amdgcn_mfma_f32_16x16x32_bf16(aq1, k1, a, 0, 0, 0);
#pragma unroll
                for (int r = 0; r < 4; ++r) {
                    float e = __builtin_amdgcn_exp2f(a[r]);
                    lsum[r] += ((mq[r] >> (nf * 16)) & 1ull) ? e : 0.f;
                }
            }
            if (g == 15) {  // end of this set's sweep: publish partial denominators
#pragma unroll
                for (int r = 0; r < 4; ++r) {
                    float l = lsum[r];
                    l += __shfl_xor(l, 1, 64);
                    l += __shfl_xor(l, 2, 64);
                    l += __shfl_xor(l, 4, 64);
                    l += __shfl_xor(l, 8, 64);
                    if (lr == 0) red[set][tbw][rh][lk * 4 + r] = l;
                }
            }
        } else if (half == 1 && phase >= 1) {
            const int set = phase - 1;
            const int rowbase = qblk * 64 + set * 32 + rh * 16;
            if (g == 0) {
                aq0 = *(const short8*)&QK[(size_t)(b * SEQ + rowbase + lr) * NQK + h * DH + lk * 8];
                aq1 = *(const short8*)&QK[(size_t)(b * SEQ + rowbase + lr) * NQK + h * DH + 32 + lk * 8];
#pragma unroll
                for (int r = 0; r < 4; ++r)
                    inv[r] = 1.0f / (red[set][0][rh][lk * 4 + r] + red[set][1][rh][lk * 4 + r]);
            }
            unsigned long long mq[4];
#pragma unroll
            for (int r = 0; r < 4; ++r) {
                int q = rowbase + lk * 4 + r;
                mq[r] = Mb[mrow0 + (size_t)q * 32 + g * 2 + tbw] >> lr;
            }
#pragma unroll
            for (int nf = 0; nf < 4; ++nf) {
                short8 k0 = *(short8*)&Ks[tbw][(nf * 16 + lr) * 72 + lk * 8];
                short8 k1 = *(short8*)&Ks[tbw][(nf * 16 + lr) * 72 + 32 + lk * 8];
                f32x4 a = {0.f, 0.f, 0.f, 0.f};
                a = __builtin_amdgcn_mfma_f32_16x16x32_bf16(aq0, k0, a, 0, 0, 0);
                a = __builtin_amdgcn_mfma_f32_16x16x32_bf16(aq1, k1, a, 0, 0, 0);
#pragma unroll
                for (int r = 0; r < 4; ++r) {
                    float p = __builtin_amdgcn_exp2f(a[r]) * inv[r];
                    Pb[(rh * 16 + lk * 4 + r) * 132 + tbw * 64 + nf * 16 + lr] =
                        ((mq[r] >> (nf * 16)) & 1ull) ? p : 0.f;
                }
            }
        }
        __syncthreads();

        // ---------- copy-out (reads Pb) + stage next group (writes Ks) ----------
        if (phase >= 1) {
            const int set = phase - 1;
            const size_t obase = ((size_t)((b * NUM_HEADS + h) * SEQ) + qblk * 64 + set * 32) * SEQ;
            int row = t >> 4;          // 0..31
            int col = (t & 15) * 8;    // 0..120
            f32x4 v0 = *(f32x4*)&Pb[row * 132 + col];
            f32x4 v1 = *(f32x4*)&Pb[row * 132 + col + 4];
            *(f32x4*)&out[obase + (size_t)row * SEQ + g * 128 + col] = v0;
            *(f32x4*)&out[obase + (size_t)row * SEQ + g * 128 + col + 4] = v1;
        }
        if (gg < 47) STAGE((g + 1) & 15)
        __syncthreads();
    }
#undef STAGE
}

extern "C" void kernel_launch(void* const* d_in, const int* in_sizes, int n_in,
                              void* d_out, int out_size, void* d_ws, size_t ws_size,
                              hipStream_t stream) {
    (void)in_sizes; (void)n_in; (void)out_size; (void)ws_size;
    const float* x = (const float*)d_in[0];
    const int* mask = (const int*)d_in[1];
    const float* Wq = (const float*)d_in[2];
    const float* bq = (const float*)d_in[3];
    const float* Wk = (const float*)d_in[4];
    const float* bk = (const float*)d_in[5];
    float* out = (float*)d_out;

    short* Wt = (short*)d_ws;                           // 1536*768 bf16
    short* QK = Wt + (size_t)NQK * DM;                  // 4096*1536 bf16
    unsigned long long* Mb =
        (unsigned long long*)(QK + (size_t)BATCH * SEQ * NQK);  // 131072 u64

    prep_kernel<<<dim3(1152 + 4096), 256, 0, stream>>>(Wq, Wk, mask, Wt, Mb);
    proj_kernel<<<dim3(BATCH * SEQ / 128, NQK / 128), 256, 0, stream>>>(x, Wt, bq, bk, QK);
    attn_kernel<<<dim3(768), 512, 0, stream>>>(QK, Mb, out);
}